// Round 5
// baseline (709.558 us; speedup 1.0000x reference)
//
#include <hip/hip_runtime.h>
#include <math.h>

namespace {
constexpr int LSEQ = 32;
constexpr int CDIM = 64;
constexpr int HDIM = 128;
constexpr int FDIM = 32;
constexpr float TWO_PI = 6.28318530717958647692f;

__device__ __forceinline__ float sigf(float x) { return 1.0f / (1.0f + __expf(-x)); }
__device__ __forceinline__ float tanh_fast(float x) { return 1.0f - 2.0f / (__expf(2.0f * x) + 1.0f); }
}

// S=4 sequences/block, 256 blocks (1/CU), 512 threads (8 waves, 2/SIMD).
// Proven R3 frame; mogrify via shfl-reduce (1 barrier/phase), gates 2-col
// float2 + k-half shfl split, out 2-col float2, x prefetch by gate-idle wave.
__global__ __launch_bounds__(512, 1)
void sfm_lstm_r5(const float* __restrict__ x,
                 const float* __restrict__ Q, const float* __restrict__ R,
                 const float* __restrict__ Wi, const float* __restrict__ bi,
                 const float* __restrict__ Wg, const float* __restrict__ bg,
                 const float* __restrict__ Wste, const float* __restrict__ bste,
                 const float* __restrict__ Wfre, const float* __restrict__ bfre,
                 const float* __restrict__ Wom, const float* __restrict__ bom,
                 const float* __restrict__ Wo, const float* __restrict__ bo,
                 const float* __restrict__ Wa, const float* __restrict__ ba,
                 const float* __restrict__ Wout, const float* __restrict__ bout,
                 float* __restrict__ out)
{
    const int t = threadIdx.x;
    const int blk = blockIdx.x;

    __shared__ float sQt[CDIM * HDIM];                 // Q^T: sQt[c*128 + k]
    __shared__ float sRt[HDIM * CDIM];                 // R^T: sRt[j*64 + k]
    // soh[320][4]: rows 0..63 = xt, 64..191 = h, 192..319 = c_t  ([dim][seq])
    __shared__ __align__(16) float soh[320][4];
    __shared__ __align__(16) float sit[HDIM][4];
    __shared__ __align__(16) float schat[HDIM][4];
    __shared__ __align__(16) float sfste[HDIM][4];
    __shared__ __align__(16) float sffre[FDIM][4];
    __shared__ __align__(16) float scosv[FDIM][4];
    __shared__ __align__(16) float ssinv[FDIM][4];
    __shared__ __align__(16) float spart[4096];        // out partials 8x512
    __shared__ float swa[FDIM];

    // stage transposed weights (one-time; staging write conflicts are negligible)
    #pragma unroll
    for (int i = 0; i < 16; ++i) {
        const int idx = t + 512 * i;
        sQt[(idx & 63) * HDIM + (idx >> 6)] = Q[idx];          // Q[k][c] -> sQt[c][k]
        sRt[(idx & 127) * CDIM + (idx >> 7)] = R[idx];         // R[k][j] -> sRt[j][k]
    }
    if (t < FDIM) swa[t] = Wa[t];
    soh[64 + (t >> 2)][t & 3] = 0.0f;                  // h = 0 (128 rows x 4)

    // per-thread complex state: (row r7, seq sA)
    const int r7 = t & 127, sA = t >> 7;
    float re[FDIM], im[FDIM];
    #pragma unroll
    for (int f = 0; f < FDIM; ++f) { re[f] = 0.0f; im[f] = 0.0f; }

    // gate roles: threads 0..447 (waves 0-6): col pair p = t>>1, k-half kh = t&1
    const int p = t >> 1, kh = t & 1;
    const float* wG = nullptr; const float* bG = nullptr;
    int strG = HDIM, j0 = 0, reg = -1;
    if      (p < 64)  { wG = Wi;   bG = bi;   strG = HDIM; j0 = 2 * p;         reg = 0; }
    else if (p < 128) { wG = Wg;   bG = bg;   strG = HDIM; j0 = 2 * (p - 64);  reg = 1; }
    else if (p < 192) { wG = Wste; bG = bste; strG = HDIM; j0 = 2 * (p - 128); reg = 2; }
    else if (p < 208) { wG = Wfre; bG = bfre; strG = FDIM; j0 = 2 * (p - 192); reg = 3; }
    else if (p < 224) { wG = Wom;  bG = bom;  strG = FDIM; j0 = 2 * (p - 208); reg = 4; }
    const float gb0 = (reg >= 0) ? bG[j0] : 0.0f;
    const float gb1 = (reg >= 0) ? bG[j0 + 1] : 0.0f;
    const float* wGp0 = (reg >= 0) ? (wG + (size_t)kh * 96 * strG + j0) : Wi;

    const float ba0 = ba[0];
    const float bo_r = bo[t >> 2];
    const float* xbase = x + (size_t)blk * 4 * LSEQ * CDIM;

    // mogrify roles
    const int mc = t >> 3, moct = t & 7;               // x-phase: col mc, k = moct + 8*kk
    const int mj = t >> 2, mquad = t & 3;              // h-phase: col mj, k = mquad + 4*kk

    // out roles: cols (2*oc2, 2*oc2+1), k-slice oks (wave-uniform)
    const int oc2 = t & 63, oks = t >> 6;
    const float* woP = Wo + 2 * oc2;

    const int pl = t - 448;                            // prefetch lane (waves 7)

    // prologue: load x(ts=0)
    if (t < 256) soh[t & 63][t >> 6] = xbase[((t >> 6) * LSEQ) * CDIM + (t & 63)];
    __syncthreads();

    for (int ts = 0; ts < LSEQ; ++ts) {
        // ---- mogrify x,h,x,h,x : one barrier per phase ----
        #pragma unroll
        for (int m = 0; m < 5; ++m) {
            if ((m & 1) == 0) {
                // xt = 2*sig(h @ Q) * xt : roles (c, oct), k interleaved
                float a0 = 0.f, a1 = 0.f, a2 = 0.f, a3 = 0.f;
                const float* qp = &sQt[mc * HDIM + moct];
                #pragma unroll
                for (int kk = 0; kk < 16; ++kk) {
                    const int k = moct + 8 * kk;
                    const float qv = qp[8 * kk];
                    const float4 h4 = *(const float4*)&soh[64 + k][0];
                    a0 += qv * h4.x; a1 += qv * h4.y; a2 += qv * h4.z; a3 += qv * h4.w;
                }
                a0 += __shfl_xor(a0, 1); a1 += __shfl_xor(a1, 1);
                a2 += __shfl_xor(a2, 1); a3 += __shfl_xor(a3, 1);
                a0 += __shfl_xor(a0, 2); a1 += __shfl_xor(a1, 2);
                a2 += __shfl_xor(a2, 2); a3 += __shfl_xor(a3, 2);
                a0 += __shfl_xor(a0, 4); a1 += __shfl_xor(a1, 4);
                a2 += __shfl_xor(a2, 4); a3 += __shfl_xor(a3, 4);
                if (moct == 0) {
                    const float4 xo = *(const float4*)&soh[mc][0];
                    *(float4*)&soh[mc][0] = make_float4(
                        2.0f * sigf(a0) * xo.x, 2.0f * sigf(a1) * xo.y,
                        2.0f * sigf(a2) * xo.z, 2.0f * sigf(a3) * xo.w);
                }
                __syncthreads();
            } else {
                // h = 2*sig(x @ R) * h : roles (j, quad), k interleaved
                float a0 = 0.f, a1 = 0.f, a2 = 0.f, a3 = 0.f;
                const float* rp = &sRt[mj * CDIM + mquad];
                #pragma unroll
                for (int kk = 0; kk < 16; ++kk) {
                    const int k = mquad + 4 * kk;
                    const float rv = rp[4 * kk];
                    const float4 x4 = *(const float4*)&soh[k][0];
                    a0 += rv * x4.x; a1 += rv * x4.y; a2 += rv * x4.z; a3 += rv * x4.w;
                }
                a0 += __shfl_xor(a0, 1); a1 += __shfl_xor(a1, 1);
                a2 += __shfl_xor(a2, 1); a3 += __shfl_xor(a3, 1);
                a0 += __shfl_xor(a0, 2); a1 += __shfl_xor(a1, 2);
                a2 += __shfl_xor(a2, 2); a3 += __shfl_xor(a3, 2);
                if (mquad == 0) {
                    const float4 ho = *(const float4*)&soh[64 + mj][0];
                    *(float4*)&soh[64 + mj][0] = make_float4(
                        2.0f * sigf(a0) * ho.x, 2.0f * sigf(a1) * ho.y,
                        2.0f * sigf(a2) * ho.z, 2.0f * sigf(a3) * ho.w);
                }
                __syncthreads();
            }
        }

        // ---- gates (waves 0-6) + x prefetch (wave 7) ----
        float xn0 = 0.f, xn1 = 0.f, xn2 = 0.f, xn3 = 0.f;
        if (reg >= 0) {
            float g00 = 0.f, g01 = 0.f, g02 = 0.f, g03 = 0.f;
            float g10 = 0.f, g11 = 0.f, g12 = 0.f, g13 = 0.f;
            const float* wp = wGp0;
            const int kbase = kh * 96;
            #pragma unroll 8
            for (int kk = 0; kk < 96; ++kk) {
                const float2 w2 = *(const float2*)wp; wp += strG;
                const float4 i4 = *(const float4*)&soh[kbase + kk][0];
                g00 += w2.x * i4.x; g01 += w2.x * i4.y; g02 += w2.x * i4.z; g03 += w2.x * i4.w;
                g10 += w2.y * i4.x; g11 += w2.y * i4.y; g12 += w2.y * i4.z; g13 += w2.y * i4.w;
            }
            g00 += __shfl_xor(g00, 1); g01 += __shfl_xor(g01, 1);
            g02 += __shfl_xor(g02, 1); g03 += __shfl_xor(g03, 1);
            g10 += __shfl_xor(g10, 1); g11 += __shfl_xor(g11, 1);
            g12 += __shfl_xor(g12, 1); g13 += __shfl_xor(g13, 1);
            if (kh == 0) {
                g00 += gb0; g01 += gb0; g02 += gb0; g03 += gb0;
                g10 += gb1; g11 += gb1; g12 += gb1; g13 += gb1;
                if (reg == 4) {
                    const float o0 = TWO_PI * sigf(g00), o1 = TWO_PI * sigf(g01);
                    const float o2 = TWO_PI * sigf(g02), o3 = TWO_PI * sigf(g03);
                    const float q0 = TWO_PI * sigf(g10), q1 = TWO_PI * sigf(g11);
                    const float q2 = TWO_PI * sigf(g12), q3 = TWO_PI * sigf(g13);
                    *(float4*)&scosv[j0][0]     = make_float4(__cosf(o0), __cosf(o1), __cosf(o2), __cosf(o3));
                    *(float4*)&ssinv[j0][0]     = make_float4(__sinf(o0), __sinf(o1), __sinf(o2), __sinf(o3));
                    *(float4*)&scosv[j0 + 1][0] = make_float4(__cosf(q0), __cosf(q1), __cosf(q2), __cosf(q3));
                    *(float4*)&ssinv[j0 + 1][0] = make_float4(__sinf(q0), __sinf(q1), __sinf(q2), __sinf(q3));
                } else {
                    float* d = (reg == 0) ? &sit[0][0] : (reg == 1) ? &schat[0][0]
                             : (reg == 2) ? &sfste[0][0] : &sffre[0][0];
                    *(float4*)&d[j0 * 4] =
                        make_float4(sigf(g00), sigf(g01), sigf(g02), sigf(g03));
                    *(float4*)&d[(j0 + 1) * 4] =
                        make_float4(sigf(g10), sigf(g11), sigf(g12), sigf(g13));
                }
            }
        } else if (ts + 1 < LSEQ) {
            // wave 7: prefetch x(ts+1) into registers (coalesced per seq)
            xn0 = xbase[(0 * LSEQ + ts + 1) * CDIM + pl];
            xn1 = xbase[(1 * LSEQ + ts + 1) * CDIM + pl];
            xn2 = xbase[(2 * LSEQ + ts + 1) * CDIM + pl];
            xn3 = xbase[(3 * LSEQ + ts + 1) * CDIM + pl];
        }
        __syncthreads();

        // ---- complex state update + amplitude @ Wa -> c_t : (row,seq)/thread ----
        {
            const float ic = sit[r7][sA] * schat[r7][sA];
            const float fs = sfste[r7][sA];
            float acc = 0.f;
            #pragma unroll
            for (int f = 0; f < FDIM; ++f) {
                const float ft = fs * sffre[f][sA];
                const float cv = scosv[f][sA], sv = ssinv[f][sA];
                re[f] = ft * re[f] + ic * cv;
                im[f] = ft * im[f] + ic * sv;
                acc += sqrtf(re[f] * re[f] + im[f] * im[f]) * swa[f];
            }
            soh[192 + r7][sA] = tanh_fast(acc + ba0);
        }
        __syncthreads();

        // ---- o_t partial: oh(320) @ Wo, 2 cols x 8 k-slices of 40 ----
        {
            float o00 = 0.f, o01 = 0.f, o02 = 0.f, o03 = 0.f;
            float o10 = 0.f, o11 = 0.f, o12 = 0.f, o13 = 0.f;
            const int k0 = oks * 40;
            const float* wp = woP + k0 * HDIM;
            #pragma unroll 8
            for (int kk = 0; kk < 40; ++kk) {
                const float2 w2 = *(const float2*)wp; wp += HDIM;
                const float4 i4 = *(const float4*)&soh[k0 + kk][0];
                o00 += w2.x * i4.x; o01 += w2.x * i4.y; o02 += w2.x * i4.z; o03 += w2.x * i4.w;
                o10 += w2.y * i4.x; o11 += w2.y * i4.y; o12 += w2.y * i4.z; o13 += w2.y * i4.w;
            }
            *(float4*)&spart[oks * 512 + oc2 * 8]     = make_float4(o00, o01, o02, o03);
            *(float4*)&spart[oks * 512 + oc2 * 8 + 4] = make_float4(o10, o11, o12, o13);
        }
        __syncthreads();

        // ---- out reduce -> h update; wave 7 also commits prefetched x ----
        {
            float v = 0.f;
            #pragma unroll
            for (int i = 0; i < 8; ++i) v += spart[i * 512 + t];
            const float o = sigf(v + bo_r);
            soh[64 + (t >> 2)][t & 3] = o * tanh_fast(soh[192 + (t >> 2)][t & 3]);
            if (t >= 448 && ts + 1 < LSEQ) {
                soh[pl][0] = xn0; soh[pl][1] = xn1;
                soh[pl][2] = xn2; soh[pl][3] = xn3;
            }
        }
        __syncthreads();
    }

    // ---- out = h_last @ Wout + bout, one wave per sequence ----
    if (t < 256) {
        const int w = t >> 6, l = t & 63;
        float pv = soh[64 + l][w] * Wout[l] + soh[128 + l][w] * Wout[64 + l];
        #pragma unroll
        for (int off = 32; off > 0; off >>= 1) pv += __shfl_xor(pv, off);
        if (l == 0) out[blk * 4 + w] = pv + bout[0];
    }
}

extern "C" void kernel_launch(void* const* d_in, const int* in_sizes, int n_in,
                              void* d_out, int out_size, void* d_ws, size_t ws_size,
                              hipStream_t stream) {
    const float* x    = (const float*)d_in[0];
    const float* Q    = (const float*)d_in[1];
    const float* R    = (const float*)d_in[2];
    const float* Wi   = (const float*)d_in[3];
    const float* bi   = (const float*)d_in[4];
    const float* Wg   = (const float*)d_in[5];
    const float* bg   = (const float*)d_in[6];
    const float* Wste = (const float*)d_in[7];
    const float* bste = (const float*)d_in[8];
    const float* Wfre = (const float*)d_in[9];
    const float* bfre = (const float*)d_in[10];
    const float* Wom  = (const float*)d_in[11];
    const float* bom  = (const float*)d_in[12];
    const float* Wo   = (const float*)d_in[13];
    const float* bo   = (const float*)d_in[14];
    const float* Wa   = (const float*)d_in[15];
    const float* ba   = (const float*)d_in[16];
    const float* Wout = (const float*)d_in[17];
    const float* bout = (const float*)d_in[18];
    float* out = (float*)d_out;

    sfm_lstm_r5<<<dim3(256), dim3(512), 0, stream>>>(
        x, Q, R, Wi, bi, Wg, bg, Wste, bste, Wfre, bfre, Wom, bom,
        Wo, bo, Wa, ba, Wout, bout, out);
}

// Round 6
// 633.397 us; speedup vs baseline: 1.1202x; 1.1202x over previous
//
#include <hip/hip_runtime.h>
#include <math.h>

namespace {
constexpr int LSEQ = 32;
constexpr int CDIM = 64;
constexpr int HDIM = 128;
constexpr int FDIM = 32;
constexpr float TWO_PI = 6.28318530717958647692f;
constexpr int SQ_STR = 136;   // 64 rows (c) x 136: bank = 8(mc%4)+moct -> 2-way max
constexpr int SR_STR = 68;    // 128 rows (j) x 68: bank = 4(mj%8)+mquad -> 2-way max
constexpr int OP_STR = 12;    // spart group stride (48B, b128-aligned)

__device__ __forceinline__ float sigf(float x) { return 1.0f / (1.0f + __expf(-x)); }
__device__ __forceinline__ float tanh_fast(float x) { return 1.0f - 2.0f / (__expf(2.0f * x) + 1.0f); }
}

// S=4 sequences/block, 256 blocks (1/CU), 512 threads (8 waves, 2/SIMD).
// R4 structure (9 barriers/step, shfl mogrify, float2 weights, x-prefetch)
// with bank-conflict-free padded LDS layouts.
__global__ __launch_bounds__(512, 1)
void sfm_lstm_r6(const float* __restrict__ x,
                 const float* __restrict__ Q, const float* __restrict__ R,
                 const float* __restrict__ Wi, const float* __restrict__ bi,
                 const float* __restrict__ Wg, const float* __restrict__ bg,
                 const float* __restrict__ Wste, const float* __restrict__ bste,
                 const float* __restrict__ Wfre, const float* __restrict__ bfre,
                 const float* __restrict__ Wom, const float* __restrict__ bom,
                 const float* __restrict__ Wo, const float* __restrict__ bo,
                 const float* __restrict__ Wa, const float* __restrict__ ba,
                 const float* __restrict__ Wout, const float* __restrict__ bout,
                 float* __restrict__ out)
{
    const int t = threadIdx.x;
    const int blk = blockIdx.x;

    __shared__ float sQt[CDIM * SQ_STR];               // Q^T padded: sQt[c*136 + k]
    __shared__ float sRt[HDIM * SR_STR];               // R^T padded: sRt[j*68 + k]
    // soh[320][4]: rows 0..63 = xt, 64..191 = h, 192..319 = c_t  ([dim][seq])
    __shared__ __align__(16) float soh[320][4];
    __shared__ __align__(16) float sit[HDIM][4];
    __shared__ __align__(16) float schat[HDIM][4];
    __shared__ __align__(16) float sfste[HDIM][4];
    __shared__ __align__(16) float sffre[FDIM][4];
    __shared__ __align__(16) float scosv[FDIM][4];
    __shared__ __align__(16) float ssinv[FDIM][4];
    __shared__ __align__(16) float spart[8 * 64 * OP_STR];   // 24.6 KB out partials
    __shared__ float swa[FDIM];

    // stage transposed weights (one-time)
    #pragma unroll
    for (int i = 0; i < 16; ++i) {
        const int idx = t + 512 * i;
        sQt[(idx & 63) * SQ_STR + (idx >> 6)] = Q[idx];        // Q[k][c] -> sQt[c][k]
        sRt[(idx & 127) * SR_STR + (idx >> 7)] = R[idx];       // R[k][j] -> sRt[j][k]
    }
    if (t < FDIM) swa[t] = Wa[t];
    soh[64 + (t >> 2)][t & 3] = 0.0f;                  // h = 0

    // per-thread complex state: (row r7, seq sA)
    const int r7 = t & 127, sA = t >> 7;
    float re[FDIM], im[FDIM];
    #pragma unroll
    for (int f = 0; f < FDIM; ++f) { re[f] = 0.0f; im[f] = 0.0f; }

    // gate roles: threads 0..447 (waves 0-6): col pair p = t>>1, k-half kh = t&1
    const int p = t >> 1, kh = t & 1;
    const float* wG = nullptr; const float* bG = nullptr;
    int strG = HDIM, j0 = 0, reg = -1;
    if      (p < 64)  { wG = Wi;   bG = bi;   strG = HDIM; j0 = 2 * p;         reg = 0; }
    else if (p < 128) { wG = Wg;   bG = bg;   strG = HDIM; j0 = 2 * (p - 64);  reg = 1; }
    else if (p < 192) { wG = Wste; bG = bste; strG = HDIM; j0 = 2 * (p - 128); reg = 2; }
    else if (p < 208) { wG = Wfre; bG = bfre; strG = FDIM; j0 = 2 * (p - 192); reg = 3; }
    else if (p < 224) { wG = Wom;  bG = bom;  strG = FDIM; j0 = 2 * (p - 208); reg = 4; }
    const float gb0 = (reg >= 0) ? bG[j0] : 0.0f;
    const float gb1 = (reg >= 0) ? bG[j0 + 1] : 0.0f;
    const float* wGp0 = (reg >= 0) ? (wG + (size_t)kh * 96 * strG + j0) : Wi;

    const float ba0 = ba[0];
    const float bo_r = bo[t >> 2];
    const float* xbase = x + (size_t)blk * 4 * LSEQ * CDIM;

    // mogrify roles
    const int mc = t >> 3, moct = t & 7;               // x-phase: col mc, k = moct + 8*kk
    const int mj = t >> 2, mquad = t & 3;              // h-phase: col mj, k = mquad + 4*kk

    // out roles: cols (2*oc2, 2*oc2+1), k-slice oks (wave-uniform)
    const int oc2 = t & 63, oks = t >> 6;
    const float* woP = Wo + 2 * oc2;
    const int ored = (t >> 3) * OP_STR + (t & 7);      // reduce-read remap, 2-way max

    const int pl = t - 448;                            // prefetch lane (wave 7)

    // prologue: load x(ts=0)
    if (t < 256) soh[t & 63][t >> 6] = xbase[((t >> 6) * LSEQ) * CDIM + (t & 63)];
    __syncthreads();

    for (int ts = 0; ts < LSEQ; ++ts) {
        // ---- mogrify x,h,x,h,x : one barrier per phase ----
        #pragma unroll
        for (int m = 0; m < 5; ++m) {
            if ((m & 1) == 0) {
                // xt = 2*sig(h @ Q) * xt : roles (c, oct), k = moct + 8*kk
                float a0 = 0.f, a1 = 0.f, a2 = 0.f, a3 = 0.f;
                const float* qp = &sQt[mc * SQ_STR + moct];
                #pragma unroll
                for (int kk = 0; kk < 16; ++kk) {
                    const int k = moct + 8 * kk;
                    const float qv = qp[8 * kk];
                    const float4 h4 = *(const float4*)&soh[64 + k][0];
                    a0 += qv * h4.x; a1 += qv * h4.y; a2 += qv * h4.z; a3 += qv * h4.w;
                }
                a0 += __shfl_xor(a0, 1); a1 += __shfl_xor(a1, 1);
                a2 += __shfl_xor(a2, 1); a3 += __shfl_xor(a3, 1);
                a0 += __shfl_xor(a0, 2); a1 += __shfl_xor(a1, 2);
                a2 += __shfl_xor(a2, 2); a3 += __shfl_xor(a3, 2);
                a0 += __shfl_xor(a0, 4); a1 += __shfl_xor(a1, 4);
                a2 += __shfl_xor(a2, 4); a3 += __shfl_xor(a3, 4);
                if (moct == 0) {
                    const float4 xo = *(const float4*)&soh[mc][0];
                    *(float4*)&soh[mc][0] = make_float4(
                        2.0f * sigf(a0) * xo.x, 2.0f * sigf(a1) * xo.y,
                        2.0f * sigf(a2) * xo.z, 2.0f * sigf(a3) * xo.w);
                }
                __syncthreads();
            } else {
                // h = 2*sig(x @ R) * h : roles (j, quad), k = mquad + 4*kk
                float a0 = 0.f, a1 = 0.f, a2 = 0.f, a3 = 0.f;
                const float* rp = &sRt[mj * SR_STR + mquad];
                #pragma unroll
                for (int kk = 0; kk < 16; ++kk) {
                    const int k = mquad + 4 * kk;
                    const float rv = rp[4 * kk];
                    const float4 x4 = *(const float4*)&soh[k][0];
                    a0 += rv * x4.x; a1 += rv * x4.y; a2 += rv * x4.z; a3 += rv * x4.w;
                }
                a0 += __shfl_xor(a0, 1); a1 += __shfl_xor(a1, 1);
                a2 += __shfl_xor(a2, 1); a3 += __shfl_xor(a3, 1);
                a0 += __shfl_xor(a0, 2); a1 += __shfl_xor(a1, 2);
                a2 += __shfl_xor(a2, 2); a3 += __shfl_xor(a3, 2);
                if (mquad == 0) {
                    const float4 ho = *(const float4*)&soh[64 + mj][0];
                    *(float4*)&soh[64 + mj][0] = make_float4(
                        2.0f * sigf(a0) * ho.x, 2.0f * sigf(a1) * ho.y,
                        2.0f * sigf(a2) * ho.z, 2.0f * sigf(a3) * ho.w);
                }
                __syncthreads();
            }
        }

        // ---- gates (waves 0-6) + x prefetch (wave 7) ----
        float xn0 = 0.f, xn1 = 0.f, xn2 = 0.f, xn3 = 0.f;
        if (reg >= 0) {
            float g00 = 0.f, g01 = 0.f, g02 = 0.f, g03 = 0.f;
            float g10 = 0.f, g11 = 0.f, g12 = 0.f, g13 = 0.f;
            const float* wp = wGp0;
            const int kbase = kh * 96;
            #pragma unroll 8
            for (int kk = 0; kk < 96; ++kk) {
                const float2 w2 = *(const float2*)wp; wp += strG;
                const float4 i4 = *(const float4*)&soh[kbase + kk][0];
                g00 += w2.x * i4.x; g01 += w2.x * i4.y; g02 += w2.x * i4.z; g03 += w2.x * i4.w;
                g10 += w2.y * i4.x; g11 += w2.y * i4.y; g12 += w2.y * i4.z; g13 += w2.y * i4.w;
            }
            g00 += __shfl_xor(g00, 1); g01 += __shfl_xor(g01, 1);
            g02 += __shfl_xor(g02, 1); g03 += __shfl_xor(g03, 1);
            g10 += __shfl_xor(g10, 1); g11 += __shfl_xor(g11, 1);
            g12 += __shfl_xor(g12, 1); g13 += __shfl_xor(g13, 1);
            if (kh == 0) {
                g00 += gb0; g01 += gb0; g02 += gb0; g03 += gb0;
                g10 += gb1; g11 += gb1; g12 += gb1; g13 += gb1;
                if (reg == 4) {
                    const float o0 = TWO_PI * sigf(g00), o1 = TWO_PI * sigf(g01);
                    const float o2 = TWO_PI * sigf(g02), o3 = TWO_PI * sigf(g03);
                    const float q0 = TWO_PI * sigf(g10), q1 = TWO_PI * sigf(g11);
                    const float q2 = TWO_PI * sigf(g12), q3 = TWO_PI * sigf(g13);
                    *(float4*)&scosv[j0][0]     = make_float4(__cosf(o0), __cosf(o1), __cosf(o2), __cosf(o3));
                    *(float4*)&ssinv[j0][0]     = make_float4(__sinf(o0), __sinf(o1), __sinf(o2), __sinf(o3));
                    *(float4*)&scosv[j0 + 1][0] = make_float4(__cosf(q0), __cosf(q1), __cosf(q2), __cosf(q3));
                    *(float4*)&ssinv[j0 + 1][0] = make_float4(__sinf(q0), __sinf(q1), __sinf(q2), __sinf(q3));
                } else {
                    float* d = (reg == 0) ? &sit[0][0] : (reg == 1) ? &schat[0][0]
                             : (reg == 2) ? &sfste[0][0] : &sffre[0][0];
                    *(float4*)&d[j0 * 4] =
                        make_float4(sigf(g00), sigf(g01), sigf(g02), sigf(g03));
                    *(float4*)&d[(j0 + 1) * 4] =
                        make_float4(sigf(g10), sigf(g11), sigf(g12), sigf(g13));
                }
            }
        } else if (ts + 1 < LSEQ) {
            xn0 = xbase[(0 * LSEQ + ts + 1) * CDIM + pl];
            xn1 = xbase[(1 * LSEQ + ts + 1) * CDIM + pl];
            xn2 = xbase[(2 * LSEQ + ts + 1) * CDIM + pl];
            xn3 = xbase[(3 * LSEQ + ts + 1) * CDIM + pl];
        }
        __syncthreads();

        // ---- complex state update + amplitude @ Wa -> c_t : (row,seq)/thread ----
        {
            const float ic = sit[r7][sA] * schat[r7][sA];
            const float fs = sfste[r7][sA];
            float acc = 0.f;
            #pragma unroll
            for (int f = 0; f < FDIM; ++f) {
                const float ft = fs * sffre[f][sA];
                const float cv = scosv[f][sA], sv = ssinv[f][sA];
                re[f] = ft * re[f] + ic * cv;
                im[f] = ft * im[f] + ic * sv;
                acc += sqrtf(re[f] * re[f] + im[f] * im[f]) * swa[f];
            }
            soh[192 + r7][sA] = tanh_fast(acc + ba0);
        }
        __syncthreads();

        // ---- o_t partial: oh(320) @ Wo, 2 cols x 8 k-slices of 40 ----
        {
            float o00 = 0.f, o01 = 0.f, o02 = 0.f, o03 = 0.f;
            float o10 = 0.f, o11 = 0.f, o12 = 0.f, o13 = 0.f;
            const int k0 = oks * 40;
            const float* wp = woP + k0 * HDIM;
            #pragma unroll 8
            for (int kk = 0; kk < 40; ++kk) {
                const float2 w2 = *(const float2*)wp; wp += HDIM;
                const float4 i4 = *(const float4*)&soh[k0 + kk][0];
                o00 += w2.x * i4.x; o01 += w2.x * i4.y; o02 += w2.x * i4.z; o03 += w2.x * i4.w;
                o10 += w2.y * i4.x; o11 += w2.y * i4.y; o12 += w2.y * i4.z; o13 += w2.y * i4.w;
            }
            float* sp = &spart[(oks * 64 + oc2) * OP_STR];
            *(float4*)sp       = make_float4(o00, o01, o02, o03);
            *(float4*)(sp + 4) = make_float4(o10, o11, o12, o13);
        }
        __syncthreads();

        // ---- out reduce -> h update; wave 7 also commits prefetched x ----
        {
            float v = 0.f;
            #pragma unroll
            for (int i = 0; i < 8; ++i) v += spart[i * 64 * OP_STR + ored];
            const float o = sigf(v + bo_r);
            soh[64 + (t >> 2)][t & 3] = o * tanh_fast(soh[192 + (t >> 2)][t & 3]);
            if (t >= 448 && ts + 1 < LSEQ) {
                soh[pl][0] = xn0; soh[pl][1] = xn1;
                soh[pl][2] = xn2; soh[pl][3] = xn3;
            }
        }
        __syncthreads();
    }

    // ---- out = h_last @ Wout + bout, one wave per sequence ----
    if (t < 256) {
        const int w = t >> 6, l = t & 63;
        float pv = soh[64 + l][w] * Wout[l] + soh[128 + l][w] * Wout[64 + l];
        #pragma unroll
        for (int off = 32; off > 0; off >>= 1) pv += __shfl_xor(pv, off);
        if (l == 0) out[blk * 4 + w] = pv + bout[0];
    }
}

extern "C" void kernel_launch(void* const* d_in, const int* in_sizes, int n_in,
                              void* d_out, int out_size, void* d_ws, size_t ws_size,
                              hipStream_t stream) {
    const float* x    = (const float*)d_in[0];
    const float* Q    = (const float*)d_in[1];
    const float* R    = (const float*)d_in[2];
    const float* Wi   = (const float*)d_in[3];
    const float* bi   = (const float*)d_in[4];
    const float* Wg   = (const float*)d_in[5];
    const float* bg   = (const float*)d_in[6];
    const float* Wste = (const float*)d_in[7];
    const float* bste = (const float*)d_in[8];
    const float* Wfre = (const float*)d_in[9];
    const float* bfre = (const float*)d_in[10];
    const float* Wom  = (const float*)d_in[11];
    const float* bom  = (const float*)d_in[12];
    const float* Wo   = (const float*)d_in[13];
    const float* bo   = (const float*)d_in[14];
    const float* Wa   = (const float*)d_in[15];
    const float* ba   = (const float*)d_in[16];
    const float* Wout = (const float*)d_in[17];
    const float* bout = (const float*)d_in[18];
    float* out = (float*)d_out;

    sfm_lstm_r6<<<dim3(256), dim3(512), 0, stream>>>(
        x, Q, R, Wi, bi, Wg, bg, Wste, bste, Wfre, bfre, Wom, bom,
        Wo, bo, Wa, ba, Wout, bout, out);
}